// Round 4
// baseline (264.561 us; speedup 1.0000x reference)
//
#include <hip/hip_runtime.h>

#define NR 1024        // num rois
#define NFG 80         // fg classes
#define CC 81          // total classes
#define KDIM 2048
#define H1DIM 256
#define H3DIM 512
#define D4 324         // 4*81

// ---------------- fused GEMM: H1 = relu(X@w1+b1), H3 = relu(X@w3+b3) --------
// 64x64 tile, BK=32, 256 threads, 4x4 micro-tile per thread.
// grid.x: 0..3 -> H1 (N=256), 4..11 -> H3 (N=512); grid.y: M/64 = 16.
__global__ __launch_bounds__(256) void gemm2_relu_kernel(
    const float* __restrict__ A,
    const float* __restrict__ B1, const float* __restrict__ bias1, float* __restrict__ C1,
    const float* __restrict__ B2, const float* __restrict__ bias2, float* __restrict__ C2)
{
    const int bxb = blockIdx.x;
    const float* B; const float* bias; float* Cout; int Ncols; int col0;
    if (bxb < 4) { B = B1; bias = bias1; Cout = C1; Ncols = H1DIM; col0 = bxb * 64; }
    else         { B = B2; bias = bias2; Cout = C2; Ncols = H3DIM; col0 = (bxb - 4) * 64; }

    __shared__ float As[32][64];   // [k][m]
    __shared__ float Bs[32][64];   // [k][n]
    const int tid = threadIdx.x;
    const int tx = tid & 15;
    const int ty = tid >> 4;
    const int row0 = blockIdx.y * 64;

    const int la_r = tid >> 2;         // 0..63
    const int la_k = (tid & 3) * 4;    // 0,4,8,12
    const int lb_k = tid >> 4;         // 0..15
    const int lb_n = (tid & 15) * 4;   // 0..60

    float acc[4][4] = {};

    for (int k0 = 0; k0 < KDIM; k0 += 32) {
        float4 av0 = *reinterpret_cast<const float4*>(&A[(row0 + la_r) * KDIM + k0 + la_k]);
        float4 av1 = *reinterpret_cast<const float4*>(&A[(row0 + la_r) * KDIM + k0 + 16 + la_k]);
        float4 bv0 = *reinterpret_cast<const float4*>(&B[(k0 + lb_k) * Ncols + col0 + lb_n]);
        float4 bv1 = *reinterpret_cast<const float4*>(&B[(k0 + 16 + lb_k) * Ncols + col0 + lb_n]);
        __syncthreads();
        As[la_k + 0][la_r] = av0.x;
        As[la_k + 1][la_r] = av0.y;
        As[la_k + 2][la_r] = av0.z;
        As[la_k + 3][la_r] = av0.w;
        As[la_k + 16][la_r] = av1.x;
        As[la_k + 17][la_r] = av1.y;
        As[la_k + 18][la_r] = av1.z;
        As[la_k + 19][la_r] = av1.w;
        *reinterpret_cast<float4*>(&Bs[lb_k][lb_n])      = bv0;
        *reinterpret_cast<float4*>(&Bs[lb_k + 16][lb_n]) = bv1;
        __syncthreads();
#pragma unroll
        for (int kk = 0; kk < 32; kk++) {
            float4 a4 = *reinterpret_cast<const float4*>(&As[kk][ty * 4]);
            float4 b4 = *reinterpret_cast<const float4*>(&Bs[kk][tx * 4]);
            float a[4] = {a4.x, a4.y, a4.z, a4.w};
            float b[4] = {b4.x, b4.y, b4.z, b4.w};
#pragma unroll
            for (int i = 0; i < 4; i++)
#pragma unroll
                for (int j = 0; j < 4; j++)
                    acc[i][j] += a[i] * b[j];
        }
    }
#pragma unroll
    for (int i = 0; i < 4; i++) {
        int row = row0 + ty * 4 + i;
#pragma unroll
        for (int j = 0; j < 4; j++) {
            int col = col0 + tx * 4 + j;
            float v = acc[i][j] + bias[col];
            Cout[row * Ncols + col] = v > 0.f ? v : 0.f;
        }
    }
}

// ---------------- scores: softmax(H1 @ w2 + b2), store fg probs class-major ----------------
__global__ __launch_bounds__(128) void scores_softmax_kernel(
    const float* __restrict__ H1, const float* __restrict__ w2,
    const float* __restrict__ b2, float* __restrict__ probs)
{
    const int r = blockIdx.x;
    const int t = threadIdx.x;
    __shared__ float h[H1DIM];
    __shared__ float lg[CC];
    __shared__ float red[128];

    h[t]       = H1[r * H1DIM + t];
    h[t + 128] = H1[r * H1DIM + t + 128];
    __syncthreads();

    if (t < CC) {
        float acc = b2[t];
        for (int k = 0; k < H1DIM; k++) acc += h[k] * w2[k * CC + t];
        lg[t] = acc;
    }
    __syncthreads();

    red[t] = (t < CC) ? lg[t] : -1e30f;
    __syncthreads();
    for (int s = 64; s > 0; s >>= 1) {
        if (t < s) red[t] = fmaxf(red[t], red[t + s]);
        __syncthreads();
    }
    float mx = red[0];
    __syncthreads();

    float e = 0.f;
    if (t < CC) e = expf(lg[t] - mx);
    red[t] = e;
    __syncthreads();
    for (int s = 64; s > 0; s >>= 1) {
        if (t < s) red[t] += red[t + s];
        __syncthreads();
    }
    float sum = red[0];

    if (t >= 1 && t < CC) probs[(t - 1) * NR + r] = e / sum;
}

// ---------------- deltas: H3 @ w4 + b4, * BBOX_STD, bbox decode, store class-major fg boxes ----------------
__global__ __launch_bounds__(384) void deltas_decode_kernel(
    const float* __restrict__ H3, const float* __restrict__ w4,
    const float* __restrict__ b4, const float* __restrict__ rois,
    const float* __restrict__ im_info, float* __restrict__ boxes)
{
    const int r = blockIdx.x;
    const int t = threadIdx.x;
    __shared__ float h[H3DIM];
    __shared__ float dl[D4];

    for (int i = t; i < H3DIM; i += 384) h[i] = H3[r * H3DIM + i];
    __syncthreads();

    if (t < D4) {
        float acc = b4[t];
        for (int k = 0; k < H3DIM; k++) acc += h[k] * w4[k * D4 + t];
        const float stdv = ((t & 3) < 2) ? 0.1f : 0.2f;
        dl[t] = acc * stdv;
    }
    __syncthreads();

    if (t < NFG) {
        const int cls = t + 1;
        float x1 = rois[r * 5 + 1], y1 = rois[r * 5 + 2];
        float x2 = rois[r * 5 + 3], y2 = rois[r * 5 + 4];
        float wdt = x2 - x1 + 1.f, hgt = y2 - y1 + 1.f;
        float ctx = x1 + 0.5f * wdt, cty = y1 + 0.5f * hgt;
        float dx = dl[cls * 4 + 0], dy = dl[cls * 4 + 1];
        float dw = dl[cls * 4 + 2], dh = dl[cls * 4 + 3];
        float pcx = dx * wdt + ctx, pcy = dy * hgt + cty;
        float pw = expf(dw) * wdt, ph = expf(dh) * hgt;
        float Hm1 = im_info[0] - 1.f, Wm1 = im_info[1] - 1.f;
        float inv = 1.f / im_info[2];
        float b0 = fminf(fmaxf(pcx - 0.5f * pw, 0.f), Wm1) * inv;
        float b1 = fminf(fmaxf(pcy - 0.5f * ph, 0.f), Hm1) * inv;
        float b2 = fminf(fmaxf(pcx + 0.5f * pw, 0.f), Wm1) * inv;
        float b3 = fminf(fmaxf(pcy + 0.5f * ph, 0.f), Hm1) * inv;
        float* bp = &boxes[(t * NR + r) * 4];
        bp[0] = b0; bp[1] = b1; bp[2] = b2; bp[3] = b3;
    }
}

// ---------------- per-class: compact valid -> rank-sort -> bitmask NMS -> emit ----------------
// Only score>THR entries matter: invalid entries emit zero rows regardless of
// their sorted position, so we never sort the full 1024 — we compact the V valid
// entries (unordered) and compute each one's exact stable rank (score desc, idx asc).
__global__ __launch_bounds__(512) void sort_nms_kernel(
    const float* __restrict__ probs, const float* __restrict__ boxes,
    float* __restrict__ out)
{
    const int c = blockIdx.x;
    const int t = threadIdx.x;
    __shared__ float cs_sc[NR];    // compacted scores (unordered)
    __shared__ int   cs_ix[NR];    // compacted roi indices
    __shared__ float ss[NR];       // sorted scores
    __shared__ int   sx[NR];       // sorted roi indices
    __shared__ float bx[NR][4];    // boxes in sorted order
    __shared__ unsigned char keep[NR];
    __shared__ unsigned char presup[256];
    __shared__ unsigned long long intra[256][4];
    __shared__ int vcount;

    if (t == 0) vcount = 0;
    __syncthreads();

    // compact valid entries (order nondeterministic; rank-sort fixes it)
    for (int i = t; i < NR; i += 512) {
        float s = probs[c * NR + i];
        if (s > 0.05f) {
            int p = atomicAdd(&vcount, 1);
            cs_sc[p] = s; cs_ix[p] = i;
        }
    }
    __syncthreads();
    const int V = vcount;

    // exact stable rank: #{f : s_f > s_e || (s_f == s_e && idx_f < idx_e)}
    for (int e = t; e < V; e += 512) {
        const float se = cs_sc[e];
        const int   ie = cs_ix[e];
        int rank = 0;
        for (int f = 0; f < V; f++) {
            float sf = cs_sc[f];
            int   jf = cs_ix[f];
            if (sf > se || (sf == se && jf < ie)) rank++;
        }
        ss[rank] = se; sx[rank] = ie;
    }
    __syncthreads();

    // gather boxes in sorted order; init keep
    for (int i = t; i < V; i += 512) {
        const float* bp = &boxes[(c * NR + sx[i]) * 4];
        bx[i][0] = bp[0]; bx[i][1] = bp[1]; bx[i][2] = bp[2]; bx[i][3] = bp[3];
    }
    for (int i = t; i < NR; i += 512) keep[i] = 0;
    __syncthreads();

    // chunked bitmask greedy NMS over the V sorted-valid entries
    for (int cs = 0; cs < V; cs += 256) {
        const int n = min(256, V - cs);

        // phase 1: cross-chunk pre-suppression vs finalized keeps of earlier chunks
        if (t < n) {
            const int gi = cs + t;
            const float x1i = bx[gi][0], y1i = bx[gi][1], x2i = bx[gi][2], y2i = bx[gi][3];
            const float ai = (x2i - x1i + 1.f) * (y2i - y1i + 1.f);
            int s = 0;
            for (int j = 0; j < cs; j++) {
                if (keep[j]) {
                    float iw = fminf(x2i, bx[j][2]) - fmaxf(x1i, bx[j][0]) + 1.f;
                    float ih = fminf(y2i, bx[j][3]) - fmaxf(y1i, bx[j][1]) + 1.f;
                    if (iw > 0.f && ih > 0.f) {
                        float inter = iw * ih;
                        float aj = (bx[j][2] - bx[j][0] + 1.f) * (bx[j][3] - bx[j][1] + 1.f);
                        if (inter / (ai + aj - inter) > 0.3f) s = 1;
                    }
                }
            }
            presup[t] = (unsigned char)s;
        }

        // phase 2: intra-chunk overlap bits: bit jj of intra[i][w] iff iou(i, jbase+jj)>thr, j<i
        for (int task = t; task < n * 4; task += 512) {
            const int i = task >> 2, w = task & 3;
            const int gi = cs + i;
            const float x1i = bx[gi][0], y1i = bx[gi][1], x2i = bx[gi][2], y2i = bx[gi][3];
            const float ai = (x2i - x1i + 1.f) * (y2i - y1i + 1.f);
            unsigned long long bits = 0;
            const int jbase = w * 64;
            const int jmax = min(64, i - jbase);
            for (int jj = 0; jj < jmax; jj++) {
                const int gj = cs + jbase + jj;
                float iw = fminf(x2i, bx[gj][2]) - fmaxf(x1i, bx[gj][0]) + 1.f;
                float ih = fminf(y2i, bx[gj][3]) - fmaxf(y1i, bx[gj][1]) + 1.f;
                if (iw > 0.f && ih > 0.f) {
                    float inter = iw * ih;
                    float aj = (bx[gj][2] - bx[gj][0] + 1.f) * (bx[gj][3] - bx[gj][1] + 1.f);
                    if (inter / (ai + aj - inter) > 0.3f) bits |= (1ULL << jj);
                }
            }
            intra[i][w] = bits;
        }
        __syncthreads();

        // phase 3: serial kept-mask greedy scan
        if (t == 0) {
            unsigned long long kept[4] = {0ULL, 0ULL, 0ULL, 0ULL};
            for (int i = 0; i < n; i++) {
                bool k = !presup[i] &&
                         !((intra[i][0] & kept[0]) | (intra[i][1] & kept[1]) |
                           (intra[i][2] & kept[2]) | (intra[i][3] & kept[3]));
                keep[cs + i] = k ? 1 : 0;
                if (k) kept[i >> 6] |= (1ULL << (i & 63));
            }
        }
        __syncthreads();
    }

    // emit dets[c][i][6]: rows >= V and non-kept rows are zeros
    for (int i = t; i < NR; i += 512) {
        float* o = &out[(c * NR + i) * 6];
        if (i < V && keep[i]) {
            o[0] = bx[i][0]; o[1] = bx[i][1]; o[2] = bx[i][2]; o[3] = bx[i][3];
            o[4] = ss[i];    o[5] = (float)c;
        } else {
            o[0] = 0.f; o[1] = 0.f; o[2] = 0.f; o[3] = 0.f; o[4] = 0.f; o[5] = 0.f;
        }
    }
}

extern "C" void kernel_launch(void* const* d_in, const int* in_sizes, int n_in,
                              void* d_out, int out_size, void* d_ws, size_t ws_size,
                              hipStream_t stream)
{
    const float* X    = (const float*)d_in[0];
    const float* rois = (const float*)d_in[1];
    const float* imi  = (const float*)d_in[2];
    const float* w1   = (const float*)d_in[3];
    const float* b1   = (const float*)d_in[4];
    const float* w2   = (const float*)d_in[5];
    const float* b2   = (const float*)d_in[6];
    const float* w3   = (const float*)d_in[7];
    const float* b3   = (const float*)d_in[8];
    const float* w4   = (const float*)d_in[9];
    const float* b4   = (const float*)d_in[10];
    float* out = (float*)d_out;

    float* ws    = (float*)d_ws;
    float* H1    = ws;                       // 1024*256
    float* H3    = H1 + NR * H1DIM;          // 1024*512
    float* probs = H3 + NR * H3DIM;          // 80*1024
    float* boxes = probs + NFG * NR;         // 80*1024*4

    gemm2_relu_kernel<<<dim3(12, NR / 64), 256, 0, stream>>>(X, w1, b1, H1, w3, b3, H3);
    scores_softmax_kernel<<<NR, 128, 0, stream>>>(H1, w2, b2, probs);
    deltas_decode_kernel<<<NR, 384, 0, stream>>>(H3, w4, b4, rois, imi, boxes);
    sort_nms_kernel<<<NFG, 512, 0, stream>>>(probs, boxes, out);
}

// Round 5
// 250.088 us; speedup vs baseline: 1.0579x; 1.0579x over previous
//
#include <hip/hip_runtime.h>

#define NR 1024        // num rois
#define NFG 80         // fg classes
#define CC 81          // total classes
#define KDIM 2048
#define H1DIM 256
#define H3DIM 512
#define D4 324         // 4*81

// ---------------- fused GEMM: H1 = relu(X@w1+b1), H3 = relu(X@w3+b3) --------
__global__ __launch_bounds__(256) void gemm2_relu_kernel(
    const float* __restrict__ A,
    const float* __restrict__ B1, const float* __restrict__ bias1, float* __restrict__ C1,
    const float* __restrict__ B2, const float* __restrict__ bias2, float* __restrict__ C2)
{
    const int bxb = blockIdx.x;
    const float* B; const float* bias; float* Cout; int Ncols; int col0;
    if (bxb < 4) { B = B1; bias = bias1; Cout = C1; Ncols = H1DIM; col0 = bxb * 64; }
    else         { B = B2; bias = bias2; Cout = C2; Ncols = H3DIM; col0 = (bxb - 4) * 64; }

    __shared__ float As[32][64];   // [k][m]
    __shared__ float Bs[32][64];   // [k][n]
    const int tid = threadIdx.x;
    const int tx = tid & 15;
    const int ty = tid >> 4;
    const int row0 = blockIdx.y * 64;

    const int la_r = tid >> 2;         // 0..63
    const int la_k = (tid & 3) * 4;    // 0,4,8,12
    const int lb_k = tid >> 4;         // 0..15
    const int lb_n = (tid & 15) * 4;   // 0..60

    float acc[4][4] = {};

    for (int k0 = 0; k0 < KDIM; k0 += 32) {
        float4 av0 = *reinterpret_cast<const float4*>(&A[(row0 + la_r) * KDIM + k0 + la_k]);
        float4 av1 = *reinterpret_cast<const float4*>(&A[(row0 + la_r) * KDIM + k0 + 16 + la_k]);
        float4 bv0 = *reinterpret_cast<const float4*>(&B[(k0 + lb_k) * Ncols + col0 + lb_n]);
        float4 bv1 = *reinterpret_cast<const float4*>(&B[(k0 + 16 + lb_k) * Ncols + col0 + lb_n]);
        __syncthreads();
        As[la_k + 0][la_r] = av0.x;
        As[la_k + 1][la_r] = av0.y;
        As[la_k + 2][la_r] = av0.z;
        As[la_k + 3][la_r] = av0.w;
        As[la_k + 16][la_r] = av1.x;
        As[la_k + 17][la_r] = av1.y;
        As[la_k + 18][la_r] = av1.z;
        As[la_k + 19][la_r] = av1.w;
        *reinterpret_cast<float4*>(&Bs[lb_k][lb_n])      = bv0;
        *reinterpret_cast<float4*>(&Bs[lb_k + 16][lb_n]) = bv1;
        __syncthreads();
#pragma unroll
        for (int kk = 0; kk < 32; kk++) {
            float4 a4 = *reinterpret_cast<const float4*>(&As[kk][ty * 4]);
            float4 b4 = *reinterpret_cast<const float4*>(&Bs[kk][tx * 4]);
            float a[4] = {a4.x, a4.y, a4.z, a4.w};
            float b[4] = {b4.x, b4.y, b4.z, b4.w};
#pragma unroll
            for (int i = 0; i < 4; i++)
#pragma unroll
                for (int j = 0; j < 4; j++)
                    acc[i][j] += a[i] * b[j];
        }
    }
#pragma unroll
    for (int i = 0; i < 4; i++) {
        int row = row0 + ty * 4 + i;
#pragma unroll
        for (int j = 0; j < 4; j++) {
            int col = col0 + tx * 4 + j;
            float v = acc[i][j] + bias[col];
            Cout[row * Ncols + col] = v > 0.f ? v : 0.f;
        }
    }
}

// ---------------- scores: softmax(H1 @ w2 + b2), store fg probs class-major ----------------
__global__ __launch_bounds__(128) void scores_softmax_kernel(
    const float* __restrict__ H1, const float* __restrict__ w2,
    const float* __restrict__ b2, float* __restrict__ probs)
{
    const int r = blockIdx.x;
    const int t = threadIdx.x;
    __shared__ float h[H1DIM];
    __shared__ float lg[CC];
    __shared__ float red[128];

    h[t]       = H1[r * H1DIM + t];
    h[t + 128] = H1[r * H1DIM + t + 128];
    __syncthreads();

    if (t < CC) {
        float acc = b2[t];
        for (int k = 0; k < H1DIM; k++) acc += h[k] * w2[k * CC + t];
        lg[t] = acc;
    }
    __syncthreads();

    red[t] = (t < CC) ? lg[t] : -1e30f;
    __syncthreads();
    for (int s = 64; s > 0; s >>= 1) {
        if (t < s) red[t] = fmaxf(red[t], red[t + s]);
        __syncthreads();
    }
    float mx = red[0];
    __syncthreads();

    float e = 0.f;
    if (t < CC) e = expf(lg[t] - mx);
    red[t] = e;
    __syncthreads();
    for (int s = 64; s > 0; s >>= 1) {
        if (t < s) red[t] += red[t + s];
        __syncthreads();
    }
    float sum = red[0];

    if (t >= 1 && t < CC) probs[(t - 1) * NR + r] = e / sum;
}

// ---------------- deltas: H3 @ w4 + b4, * BBOX_STD, bbox decode, store class-major fg boxes ----------------
__global__ __launch_bounds__(384) void deltas_decode_kernel(
    const float* __restrict__ H3, const float* __restrict__ w4,
    const float* __restrict__ b4, const float* __restrict__ rois,
    const float* __restrict__ im_info, float* __restrict__ boxes)
{
    const int r = blockIdx.x;
    const int t = threadIdx.x;
    __shared__ float h[H3DIM];
    __shared__ float dl[D4];

    for (int i = t; i < H3DIM; i += 384) h[i] = H3[r * H3DIM + i];
    __syncthreads();

    if (t < D4) {
        float acc = b4[t];
        for (int k = 0; k < H3DIM; k++) acc += h[k] * w4[k * D4 + t];
        const float stdv = ((t & 3) < 2) ? 0.1f : 0.2f;
        dl[t] = acc * stdv;
    }
    __syncthreads();

    if (t < NFG) {
        const int cls = t + 1;
        float x1 = rois[r * 5 + 1], y1 = rois[r * 5 + 2];
        float x2 = rois[r * 5 + 3], y2 = rois[r * 5 + 4];
        float wdt = x2 - x1 + 1.f, hgt = y2 - y1 + 1.f;
        float ctx = x1 + 0.5f * wdt, cty = y1 + 0.5f * hgt;
        float dx = dl[cls * 4 + 0], dy = dl[cls * 4 + 1];
        float dw = dl[cls * 4 + 2], dh = dl[cls * 4 + 3];
        float pcx = dx * wdt + ctx, pcy = dy * hgt + cty;
        float pw = expf(dw) * wdt, ph = expf(dh) * hgt;
        float Hm1 = im_info[0] - 1.f, Wm1 = im_info[1] - 1.f;
        float inv = 1.f / im_info[2];
        float b0 = fminf(fmaxf(pcx - 0.5f * pw, 0.f), Wm1) * inv;
        float b1 = fminf(fmaxf(pcy - 0.5f * ph, 0.f), Hm1) * inv;
        float b2 = fminf(fmaxf(pcx + 0.5f * pw, 0.f), Wm1) * inv;
        float b3 = fminf(fmaxf(pcy + 0.5f * ph, 0.f), Hm1) * inv;
        float* bp = &boxes[(t * NR + r) * 4];
        bp[0] = b0; bp[1] = b1; bp[2] = b2; bp[3] = b3;
    }
}

// ---------------- per-class: compact -> wave-parallel rank-sort -> ballot NMS -> emit -------
// All O(V) loops are lane-parallel (64 lanes stride the inner dim, shuffle/ballot
// reduce) so no thread ever runs a V-length serial dependent-LDS chain.
__global__ __launch_bounds__(512) void sort_nms_kernel(
    const float* __restrict__ probs, const float* __restrict__ boxes,
    float* __restrict__ out)
{
    const int c = blockIdx.x;
    const int t = threadIdx.x;
    const int lane = t & 63;
    const int wave = t >> 6;       // 0..7

    __shared__ float cs_sc[NR];    // compacted scores (unordered)
    __shared__ int   cs_ix[NR];    // compacted roi indices
    __shared__ float ss[NR];       // sorted scores
    __shared__ int   sx[NR];       // sorted roi indices
    __shared__ float bx[NR][4];    // boxes in sorted order
    __shared__ unsigned char keep[NR];
    __shared__ unsigned char presup[256];
    __shared__ unsigned long long intra[256][4];
    __shared__ int vcount;

    if (t == 0) vcount = 0;
    __syncthreads();

    // compact valid entries (order nondeterministic; rank restores determinism)
    for (int i = t; i < NR; i += 512) {
        float s = probs[c * NR + i];
        if (s > 0.05f) {
            int p = atomicAdd(&vcount, 1);
            cs_sc[p] = s; cs_ix[p] = i;
        }
    }
    __syncthreads();
    const int V = vcount;

    // wave-parallel exact stable rank: one wave per entry e, lanes stride f
    for (int e = wave; e < V; e += 8) {
        const float se = cs_sc[e];
        const int   ie = cs_ix[e];
        int cnt = 0;
        for (int f = lane; f < V; f += 64) {
            float sf = cs_sc[f];
            int   jf = cs_ix[f];
            if (sf > se || (sf == se && jf < ie)) cnt++;
        }
#pragma unroll
        for (int off = 32; off > 0; off >>= 1) cnt += __shfl_xor(cnt, off, 64);
        if (lane == 0) { ss[cnt] = se; sx[cnt] = ie; }
    }
    __syncthreads();

    // gather boxes in sorted order (float4); init keep
    for (int i = t; i < V; i += 512) {
        float4 b = *reinterpret_cast<const float4*>(&boxes[(c * NR + sx[i]) * 4]);
        bx[i][0] = b.x; bx[i][1] = b.y; bx[i][2] = b.z; bx[i][3] = b.w;
    }
    for (int i = t; i < NR; i += 512) keep[i] = 0;
    __syncthreads();

    // chunked bitmask greedy NMS over the V sorted-valid entries
    for (int cs = 0; cs < V; cs += 256) {
        const int n = min(256, V - cs);

        // phase 1+2 (wave per row i): cross-chunk presup via __any,
        // intra-chunk overlap bits via __ballot (bit jj of word w : j=w*64+jj < i, iou>thr)
        for (int i = wave; i < n; i += 8) {
            const int gi = cs + i;
            const float x1i = bx[gi][0], y1i = bx[gi][1], x2i = bx[gi][2], y2i = bx[gi][3];
            const float ai = (x2i - x1i + 1.f) * (y2i - y1i + 1.f);

            // cross-chunk: lanes stride the finalized prefix [0, cs)
            int sup = 0;
            for (int j = lane; j < cs; j += 64) {
                if (keep[j]) {
                    float iw = fminf(x2i, bx[j][2]) - fmaxf(x1i, bx[j][0]) + 1.f;
                    float ih = fminf(y2i, bx[j][3]) - fmaxf(y1i, bx[j][1]) + 1.f;
                    if (iw > 0.f && ih > 0.f) {
                        float inter = iw * ih;
                        float aj = (bx[j][2] - bx[j][0] + 1.f) * (bx[j][3] - bx[j][1] + 1.f);
                        if (inter / (ai + aj - inter) > 0.3f) sup = 1;
                    }
                }
            }
            int anysup = __any(sup);
            if (lane == 0) presup[i] = anysup ? 1 : 0;

            // intra-chunk: lane jj tests j = w*64 + jj (< i), ballot -> 64-bit word
#pragma unroll
            for (int w = 0; w < 4; w++) {
                int jj = w * 64 + lane;
                int pred = 0;
                if (jj < i) {
                    const int gj = cs + jj;
                    float iw = fminf(x2i, bx[gj][2]) - fmaxf(x1i, bx[gj][0]) + 1.f;
                    float ih = fminf(y2i, bx[gj][3]) - fmaxf(y1i, bx[gj][1]) + 1.f;
                    if (iw > 0.f && ih > 0.f) {
                        float inter = iw * ih;
                        float aj = (bx[gj][2] - bx[gj][0] + 1.f) * (bx[gj][3] - bx[gj][1] + 1.f);
                        if (inter / (ai + aj - inter) > 0.3f) pred = 1;
                    }
                }
                unsigned long long bits = __ballot(pred);
                if (lane == 0) intra[i][w] = bits;
            }
        }
        __syncthreads();

        // phase 3: serial kept-mask greedy scan (trivial, <= 256 steps)
        if (t == 0) {
            unsigned long long kept[4] = {0ULL, 0ULL, 0ULL, 0ULL};
            for (int i = 0; i < n; i++) {
                bool k = !presup[i] &&
                         !((intra[i][0] & kept[0]) | (intra[i][1] & kept[1]) |
                           (intra[i][2] & kept[2]) | (intra[i][3] & kept[3]));
                keep[cs + i] = k ? 1 : 0;
                if (k) kept[i >> 6] |= (1ULL << (i & 63));
            }
        }
        __syncthreads();
    }

    // emit dets[c][i][6]: rows >= V and non-kept rows are zeros
    for (int i = t; i < NR; i += 512) {
        float* o = &out[(c * NR + i) * 6];
        if (i < V && keep[i]) {
            o[0] = bx[i][0]; o[1] = bx[i][1]; o[2] = bx[i][2]; o[3] = bx[i][3];
            o[4] = ss[i];    o[5] = (float)c;
        } else {
            o[0] = 0.f; o[1] = 0.f; o[2] = 0.f; o[3] = 0.f; o[4] = 0.f; o[5] = 0.f;
        }
    }
}

extern "C" void kernel_launch(void* const* d_in, const int* in_sizes, int n_in,
                              void* d_out, int out_size, void* d_ws, size_t ws_size,
                              hipStream_t stream)
{
    const float* X    = (const float*)d_in[0];
    const float* rois = (const float*)d_in[1];
    const float* imi  = (const float*)d_in[2];
    const float* w1   = (const float*)d_in[3];
    const float* b1   = (const float*)d_in[4];
    const float* w2   = (const float*)d_in[5];
    const float* b2   = (const float*)d_in[6];
    const float* w3   = (const float*)d_in[7];
    const float* b3   = (const float*)d_in[8];
    const float* w4   = (const float*)d_in[9];
    const float* b4   = (const float*)d_in[10];
    float* out = (float*)d_out;

    float* ws    = (float*)d_ws;
    float* H1    = ws;                       // 1024*256
    float* H3    = H1 + NR * H1DIM;          // 1024*512
    float* probs = H3 + NR * H3DIM;          // 80*1024
    float* boxes = probs + NFG * NR;         // 80*1024*4

    gemm2_relu_kernel<<<dim3(12, NR / 64), 256, 0, stream>>>(X, w1, b1, H1, w3, b3, H3);
    scores_softmax_kernel<<<NR, 128, 0, stream>>>(H1, w2, b2, probs);
    deltas_decode_kernel<<<NR, 384, 0, stream>>>(H3, w4, b4, rois, imi, boxes);
    sort_nms_kernel<<<NFG, 512, 0, stream>>>(probs, boxes, out);
}